// Round 7
// baseline (149.145 us; speedup 1.0000x reference)
//
#include <hip/hip_runtime.h>
#include <math.h>

// GaussianSelfAttention: B=64, P=256, S=257, D=768, GRID=16.
// prepass: x,W -> f16 in MFMA-fragment-permuted unit layout for 256x256/BK64 tiles
// qkv_gemm: 256x256 tile, BK=64, 8 waves (2Mx4N, per-wave 128x64), dbuf 128KB LDS,
//           8-phase interleaved schedule (T3+T4+T5), counted vmcnt(4), conflict-free
//           linear-unit LDS (no swizzle needed), f16 MFMA.
// attn_gather: per-row corner sampling, 4-way softmax, bilinear-weighted V sum

typedef _Float16 f16x8 __attribute__((ext_vector_type(8)));
typedef _Float16 f16x4 __attribute__((ext_vector_type(4)));
typedef float    f32x4 __attribute__((ext_vector_type(4)));

#define MTOT 16448
#define DD   768
#define NC   2304
#define KT   12                  // K-tiles of 64
#define MT   65                  // tileM count (65*256 >= 16448)
#define NT9  9                   // tileN count (9*256 = 2304)
#define XU   (MT*KT*2048)        // A units (16B each)
#define WU   (NT9*KT*2048)

__global__ __launch_bounds__(256) void prepass(
    const float* __restrict__ x,
    const float* __restrict__ Wq, const float* __restrict__ Wk, const float* __restrict__ Wv,
    _Float16* __restrict__ xp, _Float16* __restrict__ wp)
{
    const int gidx = blockIdx.x * 256 + threadIdx.x;
    const float* src;
    _Float16* dst;
    if (gidx < XU) {
        const int u = gidx & 2047, kt = (gidx >> 11) % KT, tile = gidx / (KT * 2048);
        const int lane = u & 63, ks = (u >> 6) & 1, mblk = u >> 7;
        int row = tile * 256 + mblk * 16 + (lane & 15);
        row = row < MTOT ? row : MTOT - 1;
        const int col = kt * 64 + ks * 32 + (lane >> 4) * 8;
        src = x + (size_t)row * DD + col;
        dst = xp + (size_t)gidx * 8;
    } else {
        const int g = gidx - XU;
        const int u = g & 2047, kt = (g >> 11) % KT, tile = g / (KT * 2048);
        const int lane = u & 63, ks = (u >> 6) & 1, mblk = u >> 7;
        const int wrow = tile * 256 + mblk * 16 + (lane & 15);   // 0..2303
        const float* W = wrow < 768 ? Wq : (wrow < 1536 ? Wk : Wv);
        const int srow = wrow - (wrow < 768 ? 0 : (wrow < 1536 ? 768 : 1536));
        const int col = kt * 64 + ks * 32 + (lane >> 4) * 8;
        src = W + (size_t)srow * DD + col;
        dst = wp + (size_t)g * 8;
    }
    const float4 a = *(const float4*)src;
    const float4 b = *(const float4*)(src + 4);
    f16x8 o;
    o[0] = (_Float16)a.x; o[1] = (_Float16)a.y; o[2] = (_Float16)a.z; o[3] = (_Float16)a.w;
    o[4] = (_Float16)b.x; o[5] = (_Float16)b.y; o[6] = (_Float16)b.z; o[7] = (_Float16)b.w;
    *(f16x8*)dst = o;
}

#define GLD(srcp, ldsp) \
    __builtin_amdgcn_global_load_lds( \
        (const __attribute__((address_space(1))) void*)(srcp), \
        (__attribute__((address_space(3))) void*)(ldsp), 16, 0, 0)

#define PH_SYNC_IN do { \
    __builtin_amdgcn_sched_barrier(0); \
    __builtin_amdgcn_s_barrier(); \
    asm volatile("s_waitcnt lgkmcnt(0)" ::: "memory"); \
    __builtin_amdgcn_sched_barrier(0); } while (0)

#define PH_SYNC_OUT do { \
    __builtin_amdgcn_sched_barrier(0); \
    __builtin_amdgcn_s_barrier(); \
    __builtin_amdgcn_sched_barrier(0); } while (0)

#define RD_A(dst, base, c) { \
    _Pragma("unroll") for (int i = 0; i < 4; ++i) { \
        _Pragma("unroll") for (int ks = 0; ks < 2; ++ks) \
            dst[i][ks] = *(const f16x8*)(&Ax[c][(((wm*8 + (base) + i)*2 + ks)*64 + lane)*8]); } }

#define RD_B(dst, base, c) { \
    _Pragma("unroll") for (int j = 0; j < 2; ++j) { \
        _Pragma("unroll") for (int ks = 0; ks < 2; ++ks) \
            dst[j][ks] = *(const f16x8*)(&Bx[c][(((wn*4 + (base) + j)*2 + ks)*64 + lane)*8]); } }

#define MM16(av, bv, io, jo) { \
    __builtin_amdgcn_s_setprio(1); \
    _Pragma("unroll") for (int i = 0; i < 4; ++i) { \
        _Pragma("unroll") for (int j = 0; j < 2; ++j) { \
            _Pragma("unroll") for (int ks = 0; ks < 2; ++ks) \
                acc[(io)+i][(jo)+j] = __builtin_amdgcn_mfma_f32_16x16x32_f16( \
                    av[i][ks], bv[j][ks], acc[(io)+i][(jo)+j], 0, 0, 0); } } \
    __builtin_amdgcn_s_setprio(0); }

__global__ __launch_bounds__(512, 1) void qkv_gemm(
    const _Float16* __restrict__ xp, const _Float16* __restrict__ wp,
    const float* __restrict__ bq, const float* __restrict__ bk, const float* __restrict__ bv,
    _Float16* __restrict__ qkv)
{
    __shared__ __align__(16) _Float16 Ax[2][16384];   // 2 x 32KB (one K-tile each)
    __shared__ __align__(16) _Float16 Bx[2][16384];   // 2 x 32KB -> 128KB total

    // bijective XCD-chunked swizzle over 585 blocks (q=73, r=1), tileM-major
    const int bid = blockIdx.x;
    const int xcd = bid & 7, pos = bid >> 3;
    const int orig = (xcd == 0) ? pos : 74 + (xcd - 1) * 73 + pos;
    const int tileM = orig / NT9, tileN = orig % NT9;

    const int tid = threadIdx.x, lane = tid & 63, wid = tid >> 6;
    const int wm = wid >> 2, wn = wid & 3;            // 2M x 4N wave grid
    const int r16 = lane & 15, kq = lane >> 4;

    const _Float16* Asrc = xp + (size_t)tileM * KT * 16384;
    const _Float16* Bsrc = wp + (size_t)tileN * KT * 16384;

    // stage one half-tile (1024 units): 2 per-thread GLDs
    auto stA = [&](int t, int half) {
        const _Float16* s = Asrc + ((size_t)t * 2048 + half * 1024) * 8;
        #pragma unroll
        for (int l = 0; l < 2; ++l) {
            const int u = l * 512 + tid;
            GLD(s + (size_t)u * 8, &Ax[t & 1][(half * 1024 + u) * 8]);
        }
    };
    auto stB = [&](int t, int half) {
        const _Float16* s = Bsrc + ((size_t)t * 2048 + half * 1024) * 8;
        #pragma unroll
        for (int l = 0; l < 2; ++l) {
            const int u = l * 512 + tid;
            GLD(s + (size_t)u * 8, &Bx[t & 1][(half * 1024 + u) * 8]);
        }
    };

    const f32x4 zero = {0.f, 0.f, 0.f, 0.f};
    f32x4 acc[8][4];
    #pragma unroll
    for (int i = 0; i < 8; ++i)
        #pragma unroll
        for (int j = 0; j < 4; ++j) acc[i][j] = zero;

    // prologue: K0 complete + K1-B halves; vmcnt(4) -> K0 landed (K1-B in flight)
    stA(0, 0); stA(0, 1); stB(0, 0); stB(0, 1);
    stB(1, 0); stB(1, 1);
    asm volatile("s_waitcnt vmcnt(4)" ::: "memory");
    __builtin_amdgcn_sched_barrier(0);
    __builtin_amdgcn_s_barrier();
    __builtin_amdgcn_sched_barrier(0);

    #pragma unroll 1
    for (int it = 0; it < KT / 2; ++it) {
        const int t0 = 2 * it;
        const bool g2 = (t0 + 2 < KT), g3 = (t0 + 3 < KT);
        f16x8 a03[4][2], a47[4][2], b01[2][2], b23[2][2];

        // ---- group 0: K-tile t0 (buf 0) ----
        // P1
        RD_A(a03, 0, 0); RD_B(b01, 0, 0);
        stA(t0 + 1, 0);
        PH_SYNC_IN; MM16(a03, b01, 0, 0); PH_SYNC_OUT;
        // P2
        RD_B(b23, 2, 0);
        stA(t0 + 1, 1);
        PH_SYNC_IN; MM16(a03, b23, 0, 2); PH_SYNC_OUT;
        // P3
        RD_A(a47, 4, 0);
        if (g2) stB(t0 + 2, 0);
        PH_SYNC_IN; MM16(a47, b23, 4, 2); PH_SYNC_OUT;
        // P4  (counted vmcnt: A(t0+1) + all older landed; B(t0+2) may fly)
        if (g2) {
            stB(t0 + 2, 1);
            asm volatile("s_waitcnt vmcnt(4)" ::: "memory");
        } else {
            asm volatile("s_waitcnt vmcnt(0)" ::: "memory");
        }
        PH_SYNC_IN; MM16(a47, b01, 4, 0); PH_SYNC_OUT;

        // ---- group 1: K-tile t0+1 (buf 1) ----
        // P5
        RD_A(a03, 0, 1); RD_B(b01, 0, 1);
        if (g2) stA(t0 + 2, 0);
        PH_SYNC_IN; MM16(a03, b01, 0, 0); PH_SYNC_OUT;
        // P6
        RD_B(b23, 2, 1);
        if (g2) stA(t0 + 2, 1);
        PH_SYNC_IN; MM16(a03, b23, 0, 2); PH_SYNC_OUT;
        // P7
        RD_A(a47, 4, 1);
        if (g3) stB(t0 + 3, 0);
        PH_SYNC_IN; MM16(a47, b23, 4, 2); PH_SYNC_OUT;
        // P8  (counted vmcnt: K(t0+2) fully landed for next iteration)
        if (g3) stB(t0 + 3, 1);
        asm volatile("s_waitcnt vmcnt(4)" ::: "memory");
        PH_SYNC_IN; MM16(a47, b01, 4, 0); PH_SYNC_OUT;
    }

    const float* bias = tileN < 3 ? bq : (tileN < 6 ? bk : bv);
    const int bcolbase = (tileN % 3) * 256 + wn * 64;
    #pragma unroll
    for (int i = 0; i < 8; ++i) {
        const int row0 = tileM * 256 + wm * 128 + i * 16 + kq * 4;
        #pragma unroll
        for (int j = 0; j < 4; ++j) {
            const int col = tileN * 256 + wn * 64 + j * 16 + r16;
            const float bb = bias[bcolbase + j * 16 + r16];
            #pragma unroll
            for (int tt = 0; tt < 4; ++tt) {
                const int row = row0 + tt;
                if (row < MTOT)
                    qkv[(size_t)row * NC + col] = (_Float16)(acc[i][j][tt] + bb);
            }
        }
    }
}

__global__ __launch_bounds__(256) void attn_gather(
    const _Float16* __restrict__ qkv,
    const int*   __restrict__ ids,
    const float* __restrict__ avgs,
    const float* __restrict__ stds,
    const float* __restrict__ nx,
    const float* __restrict__ ny,
    float* __restrict__ out)
{
    const int tid  = threadIdx.x;
    const int lane = tid & 63;
    const int bid = blockIdx.x;
    const int swz = (bid & 7) * 514 + (bid >> 3);    // 4112 = 8*514
    const int gid = swz * 4 + (tid >> 6);
    const int b = gid / 257, s = gid % 257;
    float* orow = out + (size_t)gid * DD;

    if (s == 0) {
        const float4 one = make_float4(1.f, 1.f, 1.f, 1.f);
        #pragma unroll
        for (int j = 0; j < 3; ++j)
            *(float4*)(orow + 4 * lane + 256 * j) = one;
        return;
    }
    const int p   = s - 1;
    const int img = ids[b];
    const size_t ab = (size_t)img * 512 + p;
    const float a0 = avgs[ab], a1 = avgs[ab + 256];
    const float s0 = stds[ab], s1 = stds[ab + 256];
    const float kx = 7.5f * (1.f + tanhf((nx[b * 256 + p] + a0) * s0));
    const float ky = 7.5f * (1.f + tanhf((ny[b * 256 + p] + a1) * s1));
    const float kx1 = ceilf(kx), kx2 = floorf(kx);
    const float ky1 = ceilf(ky), ky2 = floorf(ky);
    const float cx[4] = {kx1, kx2, kx1, kx2};
    const float cy[4] = {ky1, ky1, ky2, ky2};
    int   idx[4];
    float w[4];
    #pragma unroll
    for (int n = 0; n < 4; ++n) {
        idx[n] = (int)(16.f * cy[n] + cx[n]);
        w[n]   = (1.f - fabsf(cx[n] - kx)) * (1.f - fabsf(cy[n] - ky));
    }

    const _Float16* qrow = qkv + (size_t)gid * NC;
    float qf[12];
    #pragma unroll
    for (int j = 0; j < 3; ++j) {
        const f16x4 v = *(const f16x4*)(qrow + lane * 4 + j * 256);
        qf[4 * j + 0] = (float)v[0]; qf[4 * j + 1] = (float)v[1];
        qf[4 * j + 2] = (float)v[2]; qf[4 * j + 3] = (float)v[3];
    }

    float sc[4];
    #pragma unroll
    for (int n = 0; n < 4; ++n) {
        const _Float16* krow = qkv + (size_t)(b * 257 + idx[n]) * NC + 768;
        float a = 0.f;
        #pragma unroll
        for (int j = 0; j < 3; ++j) {
            const f16x4 kv = *(const f16x4*)(krow + lane * 4 + j * 256);
            a += qf[4 * j + 0] * (float)kv[0] + qf[4 * j + 1] * (float)kv[1]
               + qf[4 * j + 2] * (float)kv[2] + qf[4 * j + 3] * (float)kv[3];
        }
        sc[n] = a;
    }
    #pragma unroll
    for (int n = 0; n < 4; ++n)
        for (int off = 32; off > 0; off >>= 1)
            sc[n] += __shfl_xor(sc[n], off);

    const float mx = fmaxf(fmaxf(sc[0], sc[1]), fmaxf(sc[2], sc[3]));
    const float e0 = expf(sc[0] - mx), e1 = expf(sc[1] - mx),
                e2 = expf(sc[2] - mx), e3 = expf(sc[3] - mx);
    const float inv = 1.f / (e0 + e1 + e2 + e3);
    const float coef[4] = {e0 * inv * w[0], e1 * inv * w[1], e2 * inv * w[2], e3 * inv * w[3]};

    const _Float16* vr0 = qkv + (size_t)(b * 257 + idx[0]) * NC + 1536;
    const _Float16* vr1 = qkv + (size_t)(b * 257 + idx[1]) * NC + 1536;
    const _Float16* vr2 = qkv + (size_t)(b * 257 + idx[2]) * NC + 1536;
    const _Float16* vr3 = qkv + (size_t)(b * 257 + idx[3]) * NC + 1536;
    #pragma unroll
    for (int j = 0; j < 3; ++j) {
        const int d = lane * 4 + j * 256;
        const f16x4 v0 = *(const f16x4*)(vr0 + d);
        const f16x4 v1 = *(const f16x4*)(vr1 + d);
        const f16x4 v2 = *(const f16x4*)(vr2 + d);
        const f16x4 v3 = *(const f16x4*)(vr3 + d);
        float4 o;
        o.x = coef[0] * (float)v0[0] + coef[1] * (float)v1[0] + coef[2] * (float)v2[0] + coef[3] * (float)v3[0];
        o.y = coef[0] * (float)v0[1] + coef[1] * (float)v1[1] + coef[2] * (float)v2[1] + coef[3] * (float)v3[1];
        o.z = coef[0] * (float)v0[2] + coef[1] * (float)v1[2] + coef[2] * (float)v2[2] + coef[3] * (float)v3[2];
        o.w = coef[0] * (float)v0[3] + coef[1] * (float)v1[3] + coef[2] * (float)v2[3] + coef[3] * (float)v3[3];
        *(float4*)(orow + d) = o;
    }
}

extern "C" void kernel_launch(void* const* d_in, const int* in_sizes, int n_in,
                              void* d_out, int out_size, void* d_ws, size_t ws_size,
                              hipStream_t stream) {
    const float* x    = (const float*)d_in[0];
    const int*   ids  = (const int*)  d_in[1];
    const float* avgs = (const float*)d_in[3];
    const float* stds = (const float*)d_in[4];
    const float* Wq   = (const float*)d_in[5];
    const float* bq   = (const float*)d_in[6];
    const float* Wk   = (const float*)d_in[7];
    const float* bk   = (const float*)d_in[8];
    const float* Wv   = (const float*)d_in[9];
    const float* bv   = (const float*)d_in[10];
    const float* nx   = (const float*)d_in[11];
    const float* ny   = (const float*)d_in[12];
    float* out = (float*)d_out;

    char* ws = (char*)d_ws;
    _Float16* qkv = (_Float16*)ws;                              // 75,792,384 B
    _Float16* xp  = (_Float16*)(ws + 75792384);                 // 25,559,040 B
    _Float16* wp  = (_Float16*)(ws + 75792384 + 25559040);      //  3,538,944 B

    prepass<<<(XU + WU) / 256, 256, 0, stream>>>(x, Wq, Wk, Wv, xp, wp);
    qkv_gemm<<<585, 512, 0, stream>>>(xp, wp, bq, bk, bv, qkv);
    attn_gather<<<4112, 256, 0, stream>>>(qkv, ids, avgs, stds, nx, ny, out);
}

// Round 8
// 133.434 us; speedup vs baseline: 1.1177x; 1.1177x over previous
//
#include <hip/hip_runtime.h>
#include <math.h>

// GaussianSelfAttention: B=64, P=256, S=257, D=768, GRID=16.
// prepass: x,W -> f16 in MFMA-fragment-permuted unit layout (r2-proven mapping)
// qkv_gemm: 128x128 tile, BK=32, r2's simple 2-syncthreads loop, SWAPPED operands
//           (A=W, B=x) so the epilogue stores 4 consecutive f16 cols per lane (8B stores)
// attn_gather: per-row corner sampling, 4-way softmax, bilinear-weighted V sum

typedef _Float16 f16x8 __attribute__((ext_vector_type(8)));
typedef _Float16 f16x4 __attribute__((ext_vector_type(4)));
typedef float    f32x4 __attribute__((ext_vector_type(4)));

#define MTOT 16448
#define DD   768
#define NC   2304
#define KT   24
#define XCH (129*24*512)
#define WCH (18*24*512)

__global__ __launch_bounds__(256) void prepass(
    const float* __restrict__ x,
    const float* __restrict__ Wq, const float* __restrict__ Wk, const float* __restrict__ Wv,
    _Float16* __restrict__ xp, _Float16* __restrict__ wp)
{
    const int gidx = blockIdx.x * 256 + threadIdx.x;
    const float* src;
    _Float16* dst;
    if (gidx < XCH) {
        const int c = gidx & 511, kk = (gidx >> 9) % KT, t = gidx / (KT * 512);
        const int row = ((c >> 6) << 4) + (c & 15);
        int gm = t * 128 + row; gm = gm < MTOT ? gm : MTOT - 1;
        src = x + (size_t)gm * DD + kk * 32 + ((c >> 4) & 3) * 8;
        dst = xp + (size_t)gidx * 8;
    } else {
        const int g = gidx - XCH;
        const int c = g & 511, kk = (g >> 9) % KT, t = g / (KT * 512);
        const int wrow = t * 128 + ((c >> 6) << 4) + (c & 15);   // 0..2303
        const float* W = wrow < 768 ? Wq : (wrow < 1536 ? Wk : Wv);
        const int srow = wrow - (wrow < 768 ? 0 : (wrow < 1536 ? 768 : 1536));
        src = W + (size_t)srow * DD + kk * 32 + ((c >> 4) & 3) * 8;
        dst = wp + (size_t)g * 8;
    }
    const float4 a = *(const float4*)src;
    const float4 b = *(const float4*)(src + 4);
    f16x8 o;
    o[0] = (_Float16)a.x; o[1] = (_Float16)a.y; o[2] = (_Float16)a.z; o[3] = (_Float16)a.w;
    o[4] = (_Float16)b.x; o[5] = (_Float16)b.y; o[6] = (_Float16)b.z; o[7] = (_Float16)b.w;
    *(f16x8*)dst = o;
}

#define GLD(srcp, ldsp) \
    __builtin_amdgcn_global_load_lds( \
        (const __attribute__((address_space(1))) void*)(srcp), \
        (__attribute__((address_space(3))) void*)(ldsp), 16, 0, 0)

__global__ __launch_bounds__(256) void qkv_gemm(
    const _Float16* __restrict__ xp, const _Float16* __restrict__ wp,
    const float* __restrict__ bq, const float* __restrict__ bk, const float* __restrict__ bv,
    _Float16* __restrict__ qkv)
{
    __shared__ __align__(16) _Float16 Wl[4096];   // 8KB: 128 W-rows x 32 k
    __shared__ __align__(16) _Float16 Xl[4096];   // 8KB: 128 x-rows x 32 k

    // bijective XCD-chunked swizzle over 2322 blocks, xtile-major
    const int bid = blockIdx.x;
    const int xcd = bid & 7, pos = bid >> 3;
    const int q8 = 2322 / 8, r8 = 2322 % 8;          // 290, 2
    const int orig = (xcd < r8) ? xcd * (q8 + 1) + pos
                                : r8 * (q8 + 1) + (xcd - r8) * q8 + pos;
    const int xtile = orig / 18, wtile = orig % 18;

    const int tid = threadIdx.x, lane = tid & 63, wid = tid >> 6;
    const int wa = wid >> 1, wb = wid & 1;            // wa: W-half, wb: x-half
    const int r16 = lane & 15, kq = lane >> 4;

    const _Float16* Xsrc = xp + (size_t)xtile * KT * 4096;
    const _Float16* Wsrc = wp + (size_t)wtile * KT * 4096;

    const f32x4 zero = {0.f, 0.f, 0.f, 0.f};
    f32x4 acc[4][4];                                   // [W-frag i][x-frag j]
    #pragma unroll
    for (int i = 0; i < 4; ++i)
        #pragma unroll
        for (int j = 0; j < 4; ++j) acc[i][j] = zero;

    for (int kk = 0; kk < KT; ++kk) {
        __syncthreads();
        #pragma unroll
        for (int g = 0; g < 2; ++g) {
            const int c0 = g * 256 + wid * 64;         // wave-uniform chunk base
            GLD(Wsrc + ((size_t)kk * 512 + c0 + lane) * 8, &Wl[c0 * 8]);
            GLD(Xsrc + ((size_t)kk * 512 + c0 + lane) * 8, &Xl[c0 * 8]);
        }
        __syncthreads();

        f16x8 a[4], b[4];
        #pragma unroll
        for (int i = 0; i < 4; ++i)
            a[i] = *(const f16x8*)(&Wl[((wa * 4 + i) * 64 + lane) * 8]);
        #pragma unroll
        for (int j = 0; j < 4; ++j)
            b[j] = *(const f16x8*)(&Xl[((wb * 4 + j) * 64 + lane) * 8]);
        #pragma unroll
        for (int i = 0; i < 4; ++i)
            #pragma unroll
            for (int j = 0; j < 4; ++j)
                acc[i][j] = __builtin_amdgcn_mfma_f32_16x16x32_f16(a[i], b[j], acc[i][j], 0, 0, 0);
    }

    // epilogue: D row-dim (register t + kq*4) = W-row = qkv COLUMN; lane dim = x-row.
    // each lane stores 4 consecutive f16 columns -> 8B store.
    const int sec = wtile / 6;
    const float* bias = sec == 0 ? bq : (sec == 1 ? bk : bv);
    #pragma unroll
    for (int i = 0; i < 4; ++i) {
        const int bcol0 = (wtile % 6) * 128 + wa * 64 + i * 16 + kq * 4;
        const int colg0 = wtile * 128 + wa * 64 + i * 16 + kq * 4;
        const float4 bb = *(const float4*)(bias + bcol0);
        #pragma unroll
        for (int j = 0; j < 4; ++j) {
            const int row = xtile * 128 + wb * 64 + j * 16 + r16;
            if (row < MTOT) {
                f16x4 o;
                o[0] = (_Float16)(acc[i][j][0] + bb.x);
                o[1] = (_Float16)(acc[i][j][1] + bb.y);
                o[2] = (_Float16)(acc[i][j][2] + bb.z);
                o[3] = (_Float16)(acc[i][j][3] + bb.w);
                *(f16x4*)(qkv + (size_t)row * NC + colg0) = o;
            }
        }
    }
}

__global__ __launch_bounds__(256) void attn_gather(
    const _Float16* __restrict__ qkv,
    const int*   __restrict__ ids,
    const float* __restrict__ avgs,
    const float* __restrict__ stds,
    const float* __restrict__ nx,
    const float* __restrict__ ny,
    float* __restrict__ out)
{
    const int tid  = threadIdx.x;
    const int lane = tid & 63;
    const int bid = blockIdx.x;
    const int swz = (bid & 7) * 514 + (bid >> 3);    // 4112 = 8*514
    const int gid = swz * 4 + (tid >> 6);
    const int b = gid / 257, s = gid % 257;
    float* orow = out + (size_t)gid * DD;

    if (s == 0) {
        const float4 one = make_float4(1.f, 1.f, 1.f, 1.f);
        #pragma unroll
        for (int j = 0; j < 3; ++j)
            *(float4*)(orow + 4 * lane + 256 * j) = one;
        return;
    }
    const int p   = s - 1;
    const int img = ids[b];
    const size_t ab = (size_t)img * 512 + p;
    const float a0 = avgs[ab], a1 = avgs[ab + 256];
    const float s0 = stds[ab], s1 = stds[ab + 256];
    const float kx = 7.5f * (1.f + tanhf((nx[b * 256 + p] + a0) * s0));
    const float ky = 7.5f * (1.f + tanhf((ny[b * 256 + p] + a1) * s1));
    const float kx1 = ceilf(kx), kx2 = floorf(kx);
    const float ky1 = ceilf(ky), ky2 = floorf(ky);
    const float cx[4] = {kx1, kx2, kx1, kx2};
    const float cy[4] = {ky1, ky1, ky2, ky2};
    int   idx[4];
    float w[4];
    #pragma unroll
    for (int n = 0; n < 4; ++n) {
        idx[n] = (int)(16.f * cy[n] + cx[n]);
        w[n]   = (1.f - fabsf(cx[n] - kx)) * (1.f - fabsf(cy[n] - ky));
    }

    const _Float16* qrow = qkv + (size_t)gid * NC;
    float qf[12];
    #pragma unroll
    for (int j = 0; j < 3; ++j) {
        const f16x4 v = *(const f16x4*)(qrow + lane * 4 + j * 256);
        qf[4 * j + 0] = (float)v[0]; qf[4 * j + 1] = (float)v[1];
        qf[4 * j + 2] = (float)v[2]; qf[4 * j + 3] = (float)v[3];
    }

    float sc[4];
    #pragma unroll
    for (int n = 0; n < 4; ++n) {
        const _Float16* krow = qkv + (size_t)(b * 257 + idx[n]) * NC + 768;
        float a = 0.f;
        #pragma unroll
        for (int j = 0; j < 3; ++j) {
            const f16x4 kv = *(const f16x4*)(krow + lane * 4 + j * 256);
            a += qf[4 * j + 0] * (float)kv[0] + qf[4 * j + 1] * (float)kv[1]
               + qf[4 * j + 2] * (float)kv[2] + qf[4 * j + 3] * (float)kv[3];
        }
        sc[n] = a;
    }
    #pragma unroll
    for (int n = 0; n < 4; ++n)
        for (int off = 32; off > 0; off >>= 1)
            sc[n] += __shfl_xor(sc[n], off);

    const float mx = fmaxf(fmaxf(sc[0], sc[1]), fmaxf(sc[2], sc[3]));
    const float e0 = expf(sc[0] - mx), e1 = expf(sc[1] - mx),
                e2 = expf(sc[2] - mx), e3 = expf(sc[3] - mx);
    const float inv = 1.f / (e0 + e1 + e2 + e3);
    const float coef[4] = {e0 * inv * w[0], e1 * inv * w[1], e2 * inv * w[2], e3 * inv * w[3]};

    const _Float16* vr0 = qkv + (size_t)(b * 257 + idx[0]) * NC + 1536;
    const _Float16* vr1 = qkv + (size_t)(b * 257 + idx[1]) * NC + 1536;
    const _Float16* vr2 = qkv + (size_t)(b * 257 + idx[2]) * NC + 1536;
    const _Float16* vr3 = qkv + (size_t)(b * 257 + idx[3]) * NC + 1536;
    #pragma unroll
    for (int j = 0; j < 3; ++j) {
        const int d = lane * 4 + j * 256;
        const f16x4 v0 = *(const f16x4*)(vr0 + d);
        const f16x4 v1 = *(const f16x4*)(vr1 + d);
        const f16x4 v2 = *(const f16x4*)(vr2 + d);
        const f16x4 v3 = *(const f16x4*)(vr3 + d);
        float4 o;
        o.x = coef[0] * (float)v0[0] + coef[1] * (float)v1[0] + coef[2] * (float)v2[0] + coef[3] * (float)v3[0];
        o.y = coef[0] * (float)v0[1] + coef[1] * (float)v1[1] + coef[2] * (float)v2[1] + coef[3] * (float)v3[1];
        o.z = coef[0] * (float)v0[2] + coef[1] * (float)v1[2] + coef[2] * (float)v2[2] + coef[3] * (float)v3[2];
        o.w = coef[0] * (float)v0[3] + coef[1] * (float)v1[3] + coef[2] * (float)v2[3] + coef[3] * (float)v3[3];
        *(float4*)(orow + d) = o;
    }
}

extern "C" void kernel_launch(void* const* d_in, const int* in_sizes, int n_in,
                              void* d_out, int out_size, void* d_ws, size_t ws_size,
                              hipStream_t stream) {
    const float* x    = (const float*)d_in[0];
    const int*   ids  = (const int*)  d_in[1];
    const float* avgs = (const float*)d_in[3];
    const float* stds = (const float*)d_in[4];
    const float* Wq   = (const float*)d_in[5];
    const float* bq   = (const float*)d_in[6];
    const float* Wk   = (const float*)d_in[7];
    const float* bk   = (const float*)d_in[8];
    const float* Wv   = (const float*)d_in[9];
    const float* bv   = (const float*)d_in[10];
    const float* nx   = (const float*)d_in[11];
    const float* ny   = (const float*)d_in[12];
    float* out = (float*)d_out;

    char* ws = (char*)d_ws;
    _Float16* qkv = (_Float16*)ws;                              // 75,792,384 B
    _Float16* xp  = (_Float16*)(ws + 75792384);                 // 25,362,432 B
    _Float16* wp  = (_Float16*)(ws + 75792384 + 25362432);      //  3,538,944 B

    prepass<<<(XCH + WCH) / 256, 256, 0, stream>>>(x, Wq, Wk, Wv, xp, wp);
    qkv_gemm<<<2322, 256, 0, stream>>>(xp, wp, bq, bk, bv, qkv);
    attn_gather<<<4112, 256, 0, stream>>>(qkv, ids, avgs, stds, nx, ny, out);
}

// Round 9
// 120.450 us; speedup vs baseline: 1.2382x; 1.1078x over previous
//
#include <hip/hip_runtime.h>
#include <math.h>

// GaussianSelfAttention: B=64, P=256, S=257, D=768, GRID=16.
// prepass: x,W -> f16 in MFMA-fragment-permuted unit layout (r2-proven mapping)
// qkv_gemm: 128x128 tile, BK=32, r2's 2-syncthreads loop, but 8 waves x (64x32)/wave
//           -> acc 32 AGPR, ~90 regs total, 4-5 waves/SIMD TLP to hide latency
// attn_gather: per-row corner sampling, 4-way softmax, bilinear-weighted V sum

typedef _Float16 f16x8 __attribute__((ext_vector_type(8)));
typedef _Float16 f16x4 __attribute__((ext_vector_type(4)));
typedef float    f32x4 __attribute__((ext_vector_type(4)));

#define MTOT 16448
#define DD   768
#define NC   2304
#define KT   24
#define XCH (129*24*512)
#define WCH (18*24*512)

__global__ __launch_bounds__(256) void prepass(
    const float* __restrict__ x,
    const float* __restrict__ Wq, const float* __restrict__ Wk, const float* __restrict__ Wv,
    _Float16* __restrict__ xp, _Float16* __restrict__ wp)
{
    const int gidx = blockIdx.x * 256 + threadIdx.x;
    const float* src;
    _Float16* dst;
    if (gidx < XCH) {
        const int c = gidx & 511, kk = (gidx >> 9) % KT, t = gidx / (KT * 512);
        const int row = ((c >> 6) << 4) + (c & 15);
        int gm = t * 128 + row; gm = gm < MTOT ? gm : MTOT - 1;
        src = x + (size_t)gm * DD + kk * 32 + ((c >> 4) & 3) * 8;
        dst = xp + (size_t)gidx * 8;
    } else {
        const int g = gidx - XCH;
        const int c = g & 511, kk = (g >> 9) % KT, t = g / (KT * 512);
        const int wrow = t * 128 + ((c >> 6) << 4) + (c & 15);   // 0..2303
        const float* W = wrow < 768 ? Wq : (wrow < 1536 ? Wk : Wv);
        const int srow = wrow - (wrow < 768 ? 0 : (wrow < 1536 ? 768 : 1536));
        src = W + (size_t)srow * DD + kk * 32 + ((c >> 4) & 3) * 8;
        dst = wp + (size_t)g * 8;
    }
    const float4 a = *(const float4*)src;
    const float4 b = *(const float4*)(src + 4);
    f16x8 o;
    o[0] = (_Float16)a.x; o[1] = (_Float16)a.y; o[2] = (_Float16)a.z; o[3] = (_Float16)a.w;
    o[4] = (_Float16)b.x; o[5] = (_Float16)b.y; o[6] = (_Float16)b.z; o[7] = (_Float16)b.w;
    *(f16x8*)dst = o;
}

#define GLD(srcp, ldsp) \
    __builtin_amdgcn_global_load_lds( \
        (const __attribute__((address_space(1))) void*)(srcp), \
        (__attribute__((address_space(3))) void*)(ldsp), 16, 0, 0)

__global__ __launch_bounds__(512, 4) void qkv_gemm(
    const _Float16* __restrict__ xp, const _Float16* __restrict__ wp,
    const float* __restrict__ bq, const float* __restrict__ bk, const float* __restrict__ bv,
    _Float16* __restrict__ qkv)
{
    __shared__ __align__(16) _Float16 Ax[4096];   // 8KB: x tile 128x32
    __shared__ __align__(16) _Float16 Bx[4096];   // 8KB: W tile 128x32

    // bijective XCD-chunked swizzle over 2322 blocks, tileM-major
    const int bid = blockIdx.x;
    const int xcd = bid & 7, pos = bid >> 3;
    const int q8 = 2322 / 8, r8 = 2322 % 8;          // 290, 2
    const int orig = (xcd < r8) ? xcd * (q8 + 1) + pos
                                : r8 * (q8 + 1) + (xcd - r8) * q8 + pos;
    const int tileM = orig / 18, tileN = orig % 18;

    const int tid = threadIdx.x, lane = tid & 63, wid = tid >> 6;   // 8 waves
    const int wm = wid >> 2, wn = wid & 3;            // 2M x 4N wave grid, 64x32 each
    const int r16 = lane & 15, kq = lane >> 4;

    const _Float16* Asrc = xp + (size_t)tileM * KT * 4096;
    const _Float16* Bsrc = wp + (size_t)tileN * KT * 4096;

    const f32x4 zero = {0.f, 0.f, 0.f, 0.f};
    f32x4 acc[4][2];
    #pragma unroll
    for (int i = 0; i < 4; ++i)
        #pragma unroll
        for (int j = 0; j < 2; ++j) acc[i][j] = zero;

    for (int kk = 0; kk < KT; ++kk) {
        __syncthreads();
        // 512 threads stage 512 A-units + 512 B-units (1 GLD each)
        {
            const int c0 = wid * 64;                  // wave-uniform
            GLD(Asrc + ((size_t)kk * 512 + c0 + lane) * 8, &Ax[c0 * 8]);
            GLD(Bsrc + ((size_t)kk * 512 + c0 + lane) * 8, &Bx[c0 * 8]);
        }
        __syncthreads();

        f16x8 a[4], b[2];
        #pragma unroll
        for (int i = 0; i < 4; ++i)
            a[i] = *(const f16x8*)(&Ax[((wm * 4 + i) * 64 + lane) * 8]);
        #pragma unroll
        for (int j = 0; j < 2; ++j)
            b[j] = *(const f16x8*)(&Bx[((wn * 2 + j) * 64 + lane) * 8]);
        #pragma unroll
        for (int i = 0; i < 4; ++i)
            #pragma unroll
            for (int j = 0; j < 2; ++j)
                acc[i][j] = __builtin_amdgcn_mfma_f32_16x16x32_f16(a[i], b[j], acc[i][j], 0, 0, 0);
    }

    const int sec = tileN / 6;
    const float* bias = sec == 0 ? bq : (sec == 1 ? bk : bv);
    const int bcol0 = (tileN % 6) * 128 + wn * 32;
    #pragma unroll
    for (int i = 0; i < 4; ++i) {
        const int row0 = tileM * 128 + wm * 64 + i * 16 + kq * 4;
        #pragma unroll
        for (int j = 0; j < 2; ++j) {
            const int col = tileN * 128 + wn * 32 + j * 16 + r16;
            const float bb = bias[bcol0 + j * 16 + r16];
            #pragma unroll
            for (int tt = 0; tt < 4; ++tt) {
                const int row = row0 + tt;
                if (row < MTOT)
                    qkv[(size_t)row * NC + col] = (_Float16)(acc[i][j][tt] + bb);
            }
        }
    }
}

__global__ __launch_bounds__(256) void attn_gather(
    const _Float16* __restrict__ qkv,
    const int*   __restrict__ ids,
    const float* __restrict__ avgs,
    const float* __restrict__ stds,
    const float* __restrict__ nx,
    const float* __restrict__ ny,
    float* __restrict__ out)
{
    const int tid  = threadIdx.x;
    const int lane = tid & 63;
    const int bid = blockIdx.x;
    const int swz = (bid & 7) * 514 + (bid >> 3);    // 4112 = 8*514
    const int gid = swz * 4 + (tid >> 6);
    const int b = gid / 257, s = gid % 257;
    float* orow = out + (size_t)gid * DD;

    if (s == 0) {
        const float4 one = make_float4(1.f, 1.f, 1.f, 1.f);
        #pragma unroll
        for (int j = 0; j < 3; ++j)
            *(float4*)(orow + 4 * lane + 256 * j) = one;
        return;
    }
    const int p   = s - 1;
    const int img = ids[b];
    const size_t ab = (size_t)img * 512 + p;
    const float a0 = avgs[ab], a1 = avgs[ab + 256];
    const float s0 = stds[ab], s1 = stds[ab + 256];
    const float kx = 7.5f * (1.f + tanhf((nx[b * 256 + p] + a0) * s0));
    const float ky = 7.5f * (1.f + tanhf((ny[b * 256 + p] + a1) * s1));
    const float kx1 = ceilf(kx), kx2 = floorf(kx);
    const float ky1 = ceilf(ky), ky2 = floorf(ky);
    const float cx[4] = {kx1, kx2, kx1, kx2};
    const float cy[4] = {ky1, ky1, ky2, ky2};
    int   idx[4];
    float w[4];
    #pragma unroll
    for (int n = 0; n < 4; ++n) {
        idx[n] = (int)(16.f * cy[n] + cx[n]);
        w[n]   = (1.f - fabsf(cx[n] - kx)) * (1.f - fabsf(cy[n] - ky));
    }

    const _Float16* qrow = qkv + (size_t)gid * NC;
    float qf[12];
    #pragma unroll
    for (int j = 0; j < 3; ++j) {
        const f16x4 v = *(const f16x4*)(qrow + lane * 4 + j * 256);
        qf[4 * j + 0] = (float)v[0]; qf[4 * j + 1] = (float)v[1];
        qf[4 * j + 2] = (float)v[2]; qf[4 * j + 3] = (float)v[3];
    }

    float sc[4];
    #pragma unroll
    for (int n = 0; n < 4; ++n) {
        const _Float16* krow = qkv + (size_t)(b * 257 + idx[n]) * NC + 768;
        float a = 0.f;
        #pragma unroll
        for (int j = 0; j < 3; ++j) {
            const f16x4 kv = *(const f16x4*)(krow + lane * 4 + j * 256);
            a += qf[4 * j + 0] * (float)kv[0] + qf[4 * j + 1] * (float)kv[1]
               + qf[4 * j + 2] * (float)kv[2] + qf[4 * j + 3] * (float)kv[3];
        }
        sc[n] = a;
    }
    #pragma unroll
    for (int n = 0; n < 4; ++n)
        for (int off = 32; off > 0; off >>= 1)
            sc[n] += __shfl_xor(sc[n], off);

    const float mx = fmaxf(fmaxf(sc[0], sc[1]), fmaxf(sc[2], sc[3]));
    const float e0 = expf(sc[0] - mx), e1 = expf(sc[1] - mx),
                e2 = expf(sc[2] - mx), e3 = expf(sc[3] - mx);
    const float inv = 1.f / (e0 + e1 + e2 + e3);
    const float coef[4] = {e0 * inv * w[0], e1 * inv * w[1], e2 * inv * w[2], e3 * inv * w[3]};

    const _Float16* vr0 = qkv + (size_t)(b * 257 + idx[0]) * NC + 1536;
    const _Float16* vr1 = qkv + (size_t)(b * 257 + idx[1]) * NC + 1536;
    const _Float16* vr2 = qkv + (size_t)(b * 257 + idx[2]) * NC + 1536;
    const _Float16* vr3 = qkv + (size_t)(b * 257 + idx[3]) * NC + 1536;
    #pragma unroll
    for (int j = 0; j < 3; ++j) {
        const int d = lane * 4 + j * 256;
        const f16x4 v0 = *(const f16x4*)(vr0 + d);
        const f16x4 v1 = *(const f16x4*)(vr1 + d);
        const f16x4 v2 = *(const f16x4*)(vr2 + d);
        const f16x4 v3 = *(const f16x4*)(vr3 + d);
        float4 o;
        o.x = coef[0] * (float)v0[0] + coef[1] * (float)v1[0] + coef[2] * (float)v2[0] + coef[3] * (float)v3[0];
        o.y = coef[0] * (float)v0[1] + coef[1] * (float)v1[1] + coef[2] * (float)v2[1] + coef[3] * (float)v3[1];
        o.z = coef[0] * (float)v0[2] + coef[1] * (float)v1[2] + coef[2] * (float)v2[2] + coef[3] * (float)v3[2];
        o.w = coef[0] * (float)v0[3] + coef[1] * (float)v1[3] + coef[2] * (float)v2[3] + coef[3] * (float)v3[3];
        *(float4*)(orow + d) = o;
    }
}

extern "C" void kernel_launch(void* const* d_in, const int* in_sizes, int n_in,
                              void* d_out, int out_size, void* d_ws, size_t ws_size,
                              hipStream_t stream) {
    const float* x    = (const float*)d_in[0];
    const int*   ids  = (const int*)  d_in[1];
    const float* avgs = (const float*)d_in[3];
    const float* stds = (const float*)d_in[4];
    const float* Wq   = (const float*)d_in[5];
    const float* bq   = (const float*)d_in[6];
    const float* Wk   = (const float*)d_in[7];
    const float* bk   = (const float*)d_in[8];
    const float* Wv   = (const float*)d_in[9];
    const float* bv   = (const float*)d_in[10];
    const float* nx   = (const float*)d_in[11];
    const float* ny   = (const float*)d_in[12];
    float* out = (float*)d_out;

    char* ws = (char*)d_ws;
    _Float16* qkv = (_Float16*)ws;                              // 75,792,384 B
    _Float16* xp  = (_Float16*)(ws + 75792384);                 // 25,362,432 B
    _Float16* wp  = (_Float16*)(ws + 75792384 + 25362432);      //  3,538,944 B

    prepass<<<(XCH + WCH) / 256, 256, 0, stream>>>(x, Wq, Wk, Wv, xp, wp);
    qkv_gemm<<<2322, 512, 0, stream>>>(xp, wp, bq, bk, bv, qkv);
    attn_gather<<<4112, 256, 0, stream>>>(qkv, ids, avgs, stds, nx, ny, out);
}

// Round 10
// 113.741 us; speedup vs baseline: 1.3113x; 1.0590x over previous
//
#include <hip/hip_runtime.h>
#include <math.h>

// GaussianSelfAttention: B=64, P=256, S=257, D=768, GRID=16.
// prepass: x,W -> f16 in MFMA-fragment-permuted unit layout (r2-proven mapping)
// qkv_gemm: 128x128 tile, BK=32, 8 waves x (64x32)/wave, 3-buffer LDS rotation with
//           prefetch depth 2, counted vmcnt(2), 1 barrier/K-tile, setprio on MFMA
// attn_gather: per-row corner sampling, 4-way softmax, bilinear-weighted V sum

typedef _Float16 f16x8 __attribute__((ext_vector_type(8)));
typedef _Float16 f16x4 __attribute__((ext_vector_type(4)));
typedef float    f32x4 __attribute__((ext_vector_type(4)));

#define MTOT 16448
#define DD   768
#define NC   2304
#define KT   24
#define XCH (129*24*512)
#define WCH (18*24*512)

__global__ __launch_bounds__(256) void prepass(
    const float* __restrict__ x,
    const float* __restrict__ Wq, const float* __restrict__ Wk, const float* __restrict__ Wv,
    _Float16* __restrict__ xp, _Float16* __restrict__ wp)
{
    const int gidx = blockIdx.x * 256 + threadIdx.x;
    const float* src;
    _Float16* dst;
    if (gidx < XCH) {
        const int c = gidx & 511, kk = (gidx >> 9) % KT, t = gidx / (KT * 512);
        const int row = ((c >> 6) << 4) + (c & 15);
        int gm = t * 128 + row; gm = gm < MTOT ? gm : MTOT - 1;
        src = x + (size_t)gm * DD + kk * 32 + ((c >> 4) & 3) * 8;
        dst = xp + (size_t)gidx * 8;
    } else {
        const int g = gidx - XCH;
        const int c = g & 511, kk = (g >> 9) % KT, t = g / (KT * 512);
        const int wrow = t * 128 + ((c >> 6) << 4) + (c & 15);   // 0..2303
        const float* W = wrow < 768 ? Wq : (wrow < 1536 ? Wk : Wv);
        const int srow = wrow - (wrow < 768 ? 0 : (wrow < 1536 ? 768 : 1536));
        src = W + (size_t)srow * DD + kk * 32 + ((c >> 4) & 3) * 8;
        dst = wp + (size_t)g * 8;
    }
    const float4 a = *(const float4*)src;
    const float4 b = *(const float4*)(src + 4);
    f16x8 o;
    o[0] = (_Float16)a.x; o[1] = (_Float16)a.y; o[2] = (_Float16)a.z; o[3] = (_Float16)a.w;
    o[4] = (_Float16)b.x; o[5] = (_Float16)b.y; o[6] = (_Float16)b.z; o[7] = (_Float16)b.w;
    *(f16x8*)dst = o;
}

#define GLD(srcp, ldsp) \
    __builtin_amdgcn_global_load_lds( \
        (const __attribute__((address_space(1))) void*)(srcp), \
        (__attribute__((address_space(3))) void*)(ldsp), 16, 0, 0)

__global__ __launch_bounds__(512, 4) void qkv_gemm(
    const _Float16* __restrict__ xp, const _Float16* __restrict__ wp,
    const float* __restrict__ bq, const float* __restrict__ bk, const float* __restrict__ bv,
    _Float16* __restrict__ qkv)
{
    __shared__ __align__(16) _Float16 Ax[3][4096];   // 3 x 8KB: x tile 128x32
    __shared__ __align__(16) _Float16 Bx[3][4096];   // 3 x 8KB: W tile 128x32  -> 48KB

    // bijective XCD-chunked swizzle over 2322 blocks, tileM-major
    const int bid = blockIdx.x;
    const int xcd = bid & 7, pos = bid >> 3;
    const int q8 = 2322 / 8, r8 = 2322 % 8;          // 290, 2
    const int orig = (xcd < r8) ? xcd * (q8 + 1) + pos
                                : r8 * (q8 + 1) + (xcd - r8) * q8 + pos;
    const int tileM = orig / 18, tileN = orig % 18;

    const int tid = threadIdx.x, lane = tid & 63, wid = tid >> 6;   // 8 waves
    const int wm = wid >> 2, wn = wid & 3;            // 2M x 4N wave grid, 64x32 each
    const int r16 = lane & 15, kq = lane >> 4;

    const _Float16* Asrc = xp + (size_t)tileM * KT * 4096;
    const _Float16* Bsrc = wp + (size_t)tileN * KT * 4096;
    const int c0 = wid * 64;                          // wave-uniform staging base

    const f32x4 zero = {0.f, 0.f, 0.f, 0.f};
    f32x4 acc[4][2];
    #pragma unroll
    for (int i = 0; i < 4; ++i)
        #pragma unroll
        for (int j = 0; j < 2; ++j) acc[i][j] = zero;

    // prologue: stage K-tiles 0 and 1
    #pragma unroll
    for (int tt = 0; tt < 2; ++tt) {
        GLD(Asrc + ((size_t)tt * 512 + c0 + lane) * 8, &Ax[tt][c0 * 8]);
        GLD(Bsrc + ((size_t)tt * 512 + c0 + lane) * 8, &Bx[tt][c0 * 8]);
    }
    asm volatile("s_waitcnt vmcnt(2)" ::: "memory");   // tile 0 landed; tile 1 in flight
    __builtin_amdgcn_sched_barrier(0);
    __builtin_amdgcn_s_barrier();
    __builtin_amdgcn_sched_barrier(0);

    for (int t = 0; t < KT; ++t) {
        const int cur = t % 3;
        // prefetch depth 2: stage K-tile t+2 (lands ~2 K-tiles of compute later).
        // Safe: buf[(t+2)%3] was last read at iter t-1, and those ds_reads were
        // lgkm-drained (MFMA consumption) before the barrier at the end of t-1.
        if (t + 2 < KT) {
            const int nb = (t + 2) % 3;
            GLD(Asrc + ((size_t)(t + 2) * 512 + c0 + lane) * 8, &Ax[nb][c0 * 8]);
            GLD(Bsrc + ((size_t)(t + 2) * 512 + c0 + lane) * 8, &Bx[nb][c0 * 8]);
        }
        __builtin_amdgcn_sched_barrier(0);

        f16x8 a[4], b[2];
        #pragma unroll
        for (int i = 0; i < 4; ++i)
            a[i] = *(const f16x8*)(&Ax[cur][((wm * 4 + i) * 64 + lane) * 8]);
        #pragma unroll
        for (int j = 0; j < 2; ++j)
            b[j] = *(const f16x8*)(&Bx[cur][((wn * 2 + j) * 64 + lane) * 8]);

        __builtin_amdgcn_s_setprio(1);
        #pragma unroll
        for (int i = 0; i < 4; ++i)
            #pragma unroll
            for (int j = 0; j < 2; ++j)
                acc[i][j] = __builtin_amdgcn_mfma_f32_16x16x32_f16(a[i], b[j], acc[i][j], 0, 0, 0);
        __builtin_amdgcn_s_setprio(0);
        __builtin_amdgcn_sched_barrier(0);

        // counted wait: only GLD(t+1) must have landed; GLD(t+2) stays in flight.
        if (t + 2 < KT) {
            asm volatile("s_waitcnt vmcnt(2)" ::: "memory");
        } else if (t + 1 < KT) {
            asm volatile("s_waitcnt vmcnt(0)" ::: "memory");
        }
        if (t + 1 < KT) {
            __builtin_amdgcn_sched_barrier(0);
            __builtin_amdgcn_s_barrier();
            __builtin_amdgcn_sched_barrier(0);
        }
    }

    const int sec = tileN / 6;
    const float* bias = sec == 0 ? bq : (sec == 1 ? bk : bv);
    const int bcol0 = (tileN % 6) * 128 + wn * 32;
    #pragma unroll
    for (int i = 0; i < 4; ++i) {
        const int row0 = tileM * 128 + wm * 64 + i * 16 + kq * 4;
        #pragma unroll
        for (int j = 0; j < 2; ++j) {
            const int col = tileN * 128 + wn * 32 + j * 16 + r16;
            const float bb = bias[bcol0 + j * 16 + r16];
            #pragma unroll
            for (int tt = 0; tt < 4; ++tt) {
                const int row = row0 + tt;
                if (row < MTOT)
                    qkv[(size_t)row * NC + col] = (_Float16)(acc[i][j][tt] + bb);
            }
        }
    }
}

__global__ __launch_bounds__(256) void attn_gather(
    const _Float16* __restrict__ qkv,
    const int*   __restrict__ ids,
    const float* __restrict__ avgs,
    const float* __restrict__ stds,
    const float* __restrict__ nx,
    const float* __restrict__ ny,
    float* __restrict__ out)
{
    const int tid  = threadIdx.x;
    const int lane = tid & 63;
    const int bid = blockIdx.x;
    const int swz = (bid & 7) * 514 + (bid >> 3);    // 4112 = 8*514
    const int gid = swz * 4 + (tid >> 6);
    const int b = gid / 257, s = gid % 257;
    float* orow = out + (size_t)gid * DD;

    if (s == 0) {
        const float4 one = make_float4(1.f, 1.f, 1.f, 1.f);
        #pragma unroll
        for (int j = 0; j < 3; ++j)
            *(float4*)(orow + 4 * lane + 256 * j) = one;
        return;
    }
    const int p   = s - 1;
    const int img = ids[b];
    const size_t ab = (size_t)img * 512 + p;
    const float a0 = avgs[ab], a1 = avgs[ab + 256];
    const float s0 = stds[ab], s1 = stds[ab + 256];
    const float kx = 7.5f * (1.f + tanhf((nx[b * 256 + p] + a0) * s0));
    const float ky = 7.5f * (1.f + tanhf((ny[b * 256 + p] + a1) * s1));
    const float kx1 = ceilf(kx), kx2 = floorf(kx);
    const float ky1 = ceilf(ky), ky2 = floorf(ky);
    const float cx[4] = {kx1, kx2, kx1, kx2};
    const float cy[4] = {ky1, ky1, ky2, ky2};
    int   idx[4];
    float w[4];
    #pragma unroll
    for (int n = 0; n < 4; ++n) {
        idx[n] = (int)(16.f * cy[n] + cx[n]);
        w[n]   = (1.f - fabsf(cx[n] - kx)) * (1.f - fabsf(cy[n] - ky));
    }

    const _Float16* qrow = qkv + (size_t)gid * NC;
    float qf[12];
    #pragma unroll
    for (int j = 0; j < 3; ++j) {
        const f16x4 v = *(const f16x4*)(qrow + lane * 4 + j * 256);
        qf[4 * j + 0] = (float)v[0]; qf[4 * j + 1] = (float)v[1];
        qf[4 * j + 2] = (float)v[2]; qf[4 * j + 3] = (float)v[3];
    }

    float sc[4];
    #pragma unroll
    for (int n = 0; n < 4; ++n) {
        const _Float16* krow = qkv + (size_t)(b * 257 + idx[n]) * NC + 768;
        float a = 0.f;
        #pragma unroll
        for (int j = 0; j < 3; ++j) {
            const f16x4 kv = *(const f16x4*)(krow + lane * 4 + j * 256);
            a += qf[4 * j + 0] * (float)kv[0] + qf[4 * j + 1] * (float)kv[1]
               + qf[4 * j + 2] * (float)kv[2] + qf[4 * j + 3] * (float)kv[3];
        }
        sc[n] = a;
    }
    #pragma unroll
    for (int n = 0; n < 4; ++n)
        for (int off = 32; off > 0; off >>= 1)
            sc[n] += __shfl_xor(sc[n], off);

    const float mx = fmaxf(fmaxf(sc[0], sc[1]), fmaxf(sc[2], sc[3]));
    const float e0 = expf(sc[0] - mx), e1 = expf(sc[1] - mx),
                e2 = expf(sc[2] - mx), e3 = expf(sc[3] - mx);
    const float inv = 1.f / (e0 + e1 + e2 + e3);
    const float coef[4] = {e0 * inv * w[0], e1 * inv * w[1], e2 * inv * w[2], e3 * inv * w[3]};

    const _Float16* vr0 = qkv + (size_t)(b * 257 + idx[0]) * NC + 1536;
    const _Float16* vr1 = qkv + (size_t)(b * 257 + idx[1]) * NC + 1536;
    const _Float16* vr2 = qkv + (size_t)(b * 257 + idx[2]) * NC + 1536;
    const _Float16* vr3 = qkv + (size_t)(b * 257 + idx[3]) * NC + 1536;
    #pragma unroll
    for (int j = 0; j < 3; ++j) {
        const int d = lane * 4 + j * 256;
        const f16x4 v0 = *(const f16x4*)(vr0 + d);
        const f16x4 v1 = *(const f16x4*)(vr1 + d);
        const f16x4 v2 = *(const f16x4*)(vr2 + d);
        const f16x4 v3 = *(const f16x4*)(vr3 + d);
        float4 o;
        o.x = coef[0] * (float)v0[0] + coef[1] * (float)v1[0] + coef[2] * (float)v2[0] + coef[3] * (float)v3[0];
        o.y = coef[0] * (float)v0[1] + coef[1] * (float)v1[1] + coef[2] * (float)v2[1] + coef[3] * (float)v3[1];
        o.z = coef[0] * (float)v0[2] + coef[1] * (float)v1[2] + coef[2] * (float)v2[2] + coef[3] * (float)v3[2];
        o.w = coef[0] * (float)v0[3] + coef[1] * (float)v1[3] + coef[2] * (float)v2[3] + coef[3] * (float)v3[3];
        *(float4*)(orow + d) = o;
    }
}

extern "C" void kernel_launch(void* const* d_in, const int* in_sizes, int n_in,
                              void* d_out, int out_size, void* d_ws, size_t ws_size,
                              hipStream_t stream) {
    const float* x    = (const float*)d_in[0];
    const int*   ids  = (const int*)  d_in[1];
    const float* avgs = (const float*)d_in[3];
    const float* stds = (const float*)d_in[4];
    const float* Wq   = (const float*)d_in[5];
    const float* bq   = (const float*)d_in[6];
    const float* Wk   = (const float*)d_in[7];
    const float* bk   = (const float*)d_in[8];
    const float* Wv   = (const float*)d_in[9];
    const float* bv   = (const float*)d_in[10];
    const float* nx   = (const float*)d_in[11];
    const float* ny   = (const float*)d_in[12];
    float* out = (float*)d_out;

    char* ws = (char*)d_ws;
    _Float16* qkv = (_Float16*)ws;                              // 75,792,384 B
    _Float16* xp  = (_Float16*)(ws + 75792384);                 // 25,362,432 B
    _Float16* wp  = (_Float16*)(ws + 75792384 + 25362432);      //  3,538,944 B

    prepass<<<(XCH + WCH) / 256, 256, 0, stream>>>(x, Wq, Wk, Wv, xp, wp);
    qkv_gemm<<<2322, 512, 0, stream>>>(xp, wp, bq, bk, bv, qkv);
    attn_gather<<<4112, 256, 0, stream>>>(qkv, ids, avgs, stds, nx, ny, out);
}